// Round 1
// baseline (2456.168 us; speedup 1.0000x reference)
//
#include <hip/hip_runtime.h>
#include <math.h>

#define T_SEQ 2048
#define D_MODEL 512
#define H_HEADS 8
#define HD 64
#define NCH 32      // number of chunks
#define CSZ 64      // chunk size  (NCH*CSZ == T_SEQ)

// ---------------- K1: QKV projection (x @ W.T + b), head-major store + phi ----------------
// grid (32, 8, 3), block 256
__global__ __launch_bounds__(256) void proj_qkv_kernel(
    const float* __restrict__ x,
    const float* __restrict__ wq, const float* __restrict__ bq,
    const float* __restrict__ wk, const float* __restrict__ bk,
    const float* __restrict__ wv, const float* __restrict__ bv,
    float* __restrict__ qh, float* __restrict__ kh, float* __restrict__ vh,
    float* __restrict__ qf, float* __restrict__ kf)
{
    const int which = blockIdx.z;
    const float* W    = (which == 0) ? wq : (which == 1) ? wk : wv;
    const float* bias = (which == 0) ? bq : (which == 1) ? bk : bv;
    float* outh = (which == 0) ? qh : (which == 1) ? kh : vh;
    float* outf = (which == 0) ? qf : (which == 1) ? kf : nullptr;

    __shared__ float As[64][33];
    __shared__ float Bs[64][33];
    const int tid = threadIdx.x;
    const int m0 = blockIdx.x * 64;
    const int n0 = blockIdx.y * 64;
    const int rb = (tid >> 4) * 4;
    const int cb = (tid & 15) * 4;

    float acc[4][4] = {};
    for (int k0 = 0; k0 < D_MODEL; k0 += 32) {
        for (int l = 0; l < 2; ++l) {
            int p = tid + l * 256;          // 0..511 float4 slots (64 rows x 8)
            int row = p >> 3;
            int c4 = (p & 7) * 4;
            float4 av = *(const float4*)(x + (size_t)(m0 + row) * D_MODEL + k0 + c4);
            As[row][c4 + 0] = av.x; As[row][c4 + 1] = av.y;
            As[row][c4 + 2] = av.z; As[row][c4 + 3] = av.w;
            float4 wv4 = *(const float4*)(W + (size_t)(n0 + row) * D_MODEL + k0 + c4);
            Bs[row][c4 + 0] = wv4.x; Bs[row][c4 + 1] = wv4.y;
            Bs[row][c4 + 2] = wv4.z; Bs[row][c4 + 3] = wv4.w;
        }
        __syncthreads();
        #pragma unroll
        for (int kk = 0; kk < 32; ++kk) {
            float ar[4], br[4];
            #pragma unroll
            for (int i = 0; i < 4; ++i) ar[i] = As[rb + i][kk];
            #pragma unroll
            for (int j = 0; j < 4; ++j) br[j] = Bs[cb + j][kk];
            #pragma unroll
            for (int i = 0; i < 4; ++i)
                #pragma unroll
                for (int j = 0; j < 4; ++j)
                    acc[i][j] = fmaf(ar[i], br[j], acc[i][j]);
        }
        __syncthreads();
    }
    #pragma unroll
    for (int i = 0; i < 4; ++i) {
        int m = m0 + rb + i;
        #pragma unroll
        for (int j = 0; j < 4; ++j) {
            int n = n0 + cb + j;
            float v = acc[i][j] + bias[n];
            int h = n >> 6, d = n & 63;
            size_t idx = ((size_t)(h * T_SEQ) + m) * HD + d;
            outh[idx] = v;
            if (outf) outf[idx] = (v > 0.f) ? (v + 1.f) : expf(v);  // elu+1
        }
    }
}

// ---------------- K6: output projection (att @ wo.T + bo) ----------------
// grid (32, 8), block 256
__global__ __launch_bounds__(256) void out_proj_kernel(
    const float* __restrict__ att, const float* __restrict__ wo,
    const float* __restrict__ bo, float* __restrict__ out)
{
    __shared__ float As[64][33];
    __shared__ float Bs[64][33];
    const int tid = threadIdx.x;
    const int m0 = blockIdx.x * 64;
    const int n0 = blockIdx.y * 64;
    const int rb = (tid >> 4) * 4;
    const int cb = (tid & 15) * 4;

    float acc[4][4] = {};
    for (int k0 = 0; k0 < D_MODEL; k0 += 32) {
        for (int l = 0; l < 2; ++l) {
            int p = tid + l * 256;
            int row = p >> 3;
            int c4 = (p & 7) * 4;
            float4 av = *(const float4*)(att + (size_t)(m0 + row) * D_MODEL + k0 + c4);
            As[row][c4 + 0] = av.x; As[row][c4 + 1] = av.y;
            As[row][c4 + 2] = av.z; As[row][c4 + 3] = av.w;
            float4 wv4 = *(const float4*)(wo + (size_t)(n0 + row) * D_MODEL + k0 + c4);
            Bs[row][c4 + 0] = wv4.x; Bs[row][c4 + 1] = wv4.y;
            Bs[row][c4 + 2] = wv4.z; Bs[row][c4 + 3] = wv4.w;
        }
        __syncthreads();
        #pragma unroll
        for (int kk = 0; kk < 32; ++kk) {
            float ar[4], br[4];
            #pragma unroll
            for (int i = 0; i < 4; ++i) ar[i] = As[rb + i][kk];
            #pragma unroll
            for (int j = 0; j < 4; ++j) br[j] = Bs[cb + j][kk];
            #pragma unroll
            for (int i = 0; i < 4; ++i)
                #pragma unroll
                for (int j = 0; j < 4; ++j)
                    acc[i][j] = fmaf(ar[i], br[j], acc[i][j]);
        }
        __syncthreads();
    }
    #pragma unroll
    for (int i = 0; i < 4; ++i) {
        int m = m0 + rb + i;
        #pragma unroll
        for (int j = 0; j < 4; ++j) {
            int n = n0 + cb + j;
            out[(size_t)m * D_MODEL + n] = acc[i][j] + bo[n];
        }
    }
}

// ---------------- K2: scores + exact quantiles (bitonic sort) + critical softmax*V ----------------
// grid (2048, 8), block 256
__global__ __launch_bounds__(256) void scores_crit_kernel(
    const float* __restrict__ qh, const float* __restrict__ kh, const float* __restrict__ vh,
    float* __restrict__ att, float* __restrict__ marg)
{
    const int t = blockIdx.x;
    const int h = blockIdx.y;
    const int tid = threadIdx.x;

    __shared__ float s[T_SEQ];
    __shared__ float srt[T_SEQ];
    __shared__ float qrow[HD];
    __shared__ float red[256];

    const float* kbase = kh + (size_t)h * T_SEQ * HD;
    const float* vbase = vh + (size_t)h * T_SEQ * HD;
    if (tid < HD) qrow[tid] = qh[((size_t)h * T_SEQ + t) * HD + tid];
    __syncthreads();

    // scores s[j] = q . k_j / 8
    for (int u = 0; u < 8; ++u) {
        int j = tid + u * 256;
        const float4* kr = (const float4*)(kbase + (size_t)j * HD);
        float dot = 0.f;
        #pragma unroll
        for (int d4 = 0; d4 < 16; ++d4) {
            float4 k4 = kr[d4];
            dot += k4.x * qrow[d4 * 4 + 0] + k4.y * qrow[d4 * 4 + 1]
                 + k4.z * qrow[d4 * 4 + 2] + k4.w * qrow[d4 * 4 + 3];
        }
        float sv = dot * 0.125f;
        s[j] = sv;
        srt[j] = sv;
    }
    __syncthreads();

    // bitonic sort srt ascending (2048 elements)
    for (int k = 2; k <= T_SEQ; k <<= 1) {
        for (int j = k >> 1; j > 0; j >>= 1) {
            for (int u = 0; u < 8; ++u) {
                int i = tid + u * 256;
                int l = i ^ j;
                if (l > i) {
                    float a = srt[i], b = srt[l];
                    bool up = ((i & k) == 0);
                    if ((a > b) == up) { srt[i] = b; srt[l] = a; }
                }
            }
            __syncthreads();
        }
    }

    // exact interpolated quantiles: pos_crit = 0.95*2047 = 1944.65, pos_skip = 0.1*2047 = 204.7
    const float crit_th = srt[1944] * 0.35f + srt[1945] * 0.65f;
    const float skip_th = srt[204] * 0.30f + srt[205] * 0.70f;
    const float m = srt[T_SEQ - 1];  // global max == max over crit entries

    // single pass: marginal count, softmax partials, overwrite s with unnormalized weights
    int mcount = 0;
    float z = 0.f;
    for (int u = 0; u < 8; ++u) {
        int j = tid + u * 256;
        float sv = s[j];
        bool crit = sv > crit_th;
        bool skip = sv < skip_th;
        if (!crit && !skip) mcount++;
        float w = 0.f;
        if (crit) { w = expf(sv - m); z += w; }
        s[j] = w;
    }
    red[tid] = z;
    __syncthreads();
    for (int st = 128; st > 0; st >>= 1) {
        if (tid < st) red[tid] += red[tid + st];
        __syncthreads();
    }
    float ztot = red[0];
    __syncthreads();
    red[tid] = (float)mcount;
    __syncthreads();
    for (int st = 128; st > 0; st >>= 1) {
        if (tid < st) red[tid] += red[tid + st];
        __syncthreads();
    }
    float mfrac = red[0] * (1.0f / (float)T_SEQ);
    __syncthreads();

    // weighted V over critical entries (skip zero weights)
    const float invz = (ztot > 0.f) ? (1.f / ztot) : 0.f;
    const int e = tid >> 2;
    const int qq = tid & 3;
    float acc2 = 0.f;
    for (int j = qq * 512; j < qq * 512 + 512; ++j) {
        float w = s[j];
        if (w != 0.f) acc2 += w * vbase[(size_t)j * HD + e];
    }
    red[tid] = acc2;
    __syncthreads();
    if (tid < HD) {
        float tot = red[tid * 4] + red[tid * 4 + 1] + red[tid * 4 + 2] + red[tid * 4 + 3];
        att[(size_t)t * D_MODEL + h * HD + tid] = tot * invz;
        if (tid == 0) marg[(size_t)h * T_SEQ + t] = mfrac;
    }
}

// ---------------- K3: per-chunk sums A_c = sum kf x v, b_c = sum kf ----------------
// grid (NCH, 8), block 256
__global__ __launch_bounds__(256) void chunk_sums_kernel(
    const float* __restrict__ kf, const float* __restrict__ vh,
    float* __restrict__ Ac, float* __restrict__ bc)
{
    const int c = blockIdx.x, h = blockIdx.y;
    const int tid = threadIdx.x;
    __shared__ float kfl[CSZ][HD];
    __shared__ float vl[CSZ][HD];
    const size_t base = ((size_t)h * T_SEQ + c * CSZ) * HD;

    for (int l = 0; l < 4; ++l) {
        int p = tid + l * 256;            // float4 index over 64x16
        int row = p >> 4, c4 = (p & 15) * 4;
        *(float4*)&kfl[row][c4] = *(const float4*)(kf + base + (size_t)row * HD + c4);
        *(float4*)&vl[row][c4]  = *(const float4*)(vh + base + (size_t)row * HD + c4);
    }
    __syncthreads();

    const int d = tid >> 2, e0 = (tid & 3) * 16;
    float acc[16] = {};
    for (int u = 0; u < CSZ; ++u) {
        float a = kfl[u][d];
        #pragma unroll
        for (int i = 0; i < 16; ++i) acc[i] = fmaf(a, vl[u][e0 + i], acc[i]);
    }
    float* Adst = Ac + (((size_t)(h * NCH + c) * HD + d) * HD + e0);
    #pragma unroll
    for (int i = 0; i < 16; ++i) Adst[i] = acc[i];

    if (tid < HD) {
        float sum = 0.f;
        for (int u = 0; u < CSZ; ++u) sum += kfl[u][tid];
        bc[(size_t)(h * NCH + c) * HD + tid] = sum;
    }
}

// ---------------- K4: exclusive prefix over chunks ----------------
// grid (8), block 256
__global__ __launch_bounds__(256) void prefix_kernel(
    const float* __restrict__ Ac, const float* __restrict__ bc,
    float* __restrict__ Sx, float* __restrict__ sx)
{
    const int h = blockIdx.x;
    const int tid = threadIdx.x;
    float run[16];
    #pragma unroll
    for (int i = 0; i < 16; ++i) run[i] = 0.f;
    for (int c = 0; c < NCH; ++c) {
        const float* a = Ac + (size_t)(h * NCH + c) * 4096;
        float* sdst = Sx + (size_t)(h * NCH + c) * 4096;
        #pragma unroll
        for (int i = 0; i < 16; ++i) {
            int idx = tid + i * 256;
            sdst[idx] = run[i];
            run[i] += a[idx];
        }
    }
    if (tid < HD) {
        float rb = 0.f;
        for (int c = 0; c < NCH; ++c) {
            sx[(size_t)(h * NCH + c) * HD + tid] = rb;
            rb += bc[(size_t)(h * NCH + c) * HD + tid];
        }
    }
}

// ---------------- K5: intra-chunk causal linear attention + combine ----------------
// grid (NCH, 8), block 256
__global__ __launch_bounds__(256) void lin_combine_kernel(
    const float* __restrict__ qf, const float* __restrict__ kf, const float* __restrict__ vh,
    const float* __restrict__ Sx, const float* __restrict__ sx,
    const float* __restrict__ marg, float* __restrict__ att)
{
    const int c = blockIdx.x, h = blockIdx.y;
    const int tid = threadIdx.x;
    __shared__ float Qs[CSZ][65];
    __shared__ float Ks[CSZ][65];   // reused to hold Ss after P is computed
    __shared__ float P[CSZ][66];
    __shared__ float svv[HD];
    __shared__ float coef[CSZ];

    const size_t base = ((size_t)h * T_SEQ + c * CSZ) * HD;
    for (int l = 0; l < 4; ++l) {
        int p = tid + l * 256;
        int row = p >> 4, c4 = (p & 15) * 4;
        *(float4*)&Qs[row][c4] = *(const float4*)(qf + base + (size_t)row * HD + c4);
        *(float4*)&Ks[row][c4] = *(const float4*)(kf + base + (size_t)row * HD + c4);
    }
    if (tid < HD) svv[tid] = sx[(size_t)(h * NCH + c) * HD + tid];
    __syncthreads();

    // P[t][u] = qf_t . kf_u  (zero above diagonal)
    {
        const int tq = tid >> 2, u0 = (tid & 3) * 16;
        float pr[16];
        #pragma unroll
        for (int i = 0; i < 16; ++i) pr[i] = 0.f;
        for (int d = 0; d < HD; ++d) {
            float qv = Qs[tq][d];
            #pragma unroll
            for (int i = 0; i < 16; ++i) pr[i] = fmaf(qv, Ks[u0 + i][d], pr[i]);
        }
        #pragma unroll
        for (int i = 0; i < 16; ++i) P[tq][u0 + i] = (u0 + i <= tq) ? pr[i] : 0.f;
    }
    __syncthreads();

    // denominator + coefficient (threads 0..63), and load Ss into Ks (all threads)
    if (tid < CSZ) {
        const int tq = tid;
        float den = 0.f;
        for (int d = 0; d < HD; ++d) den += Qs[tq][d] * svv[d];
        for (int u = 0; u <= tq; ++u) den += P[tq][u];
        den = fmaxf(den, 1e-6f);
        coef[tq] = marg[(size_t)h * T_SEQ + c * CSZ + tq] / den;
    }
    {
        const float* Sbase = Sx + (size_t)(h * NCH + c) * 4096;
        for (int l = 0; l < 4; ++l) {
            int p = tid + l * 256;
            int row = p >> 4, c4 = (p & 15) * 4;
            *(float4*)&Ks[row][c4] = *(const float4*)(Sbase + (size_t)row * HD + c4);
        }
    }
    __syncthreads();

    // lin_num = qf @ Ss + P @ v ; write out scaled
    {
        const int tq = tid >> 2, e0 = (tid & 3) * 16;
        float acc[16];
        #pragma unroll
        for (int i = 0; i < 16; ++i) acc[i] = 0.f;
        for (int d = 0; d < HD; ++d) {
            float qv = Qs[tq][d];
            #pragma unroll
            for (int i = 0; i < 16; ++i) acc[i] = fmaf(qv, Ks[d][e0 + i], acc[i]);
        }
        const float* vb = vh + base;
        for (int u = 0; u <= tq; ++u) {
            float pv = P[tq][u];
            #pragma unroll
            for (int i = 0; i < 16; ++i) acc[i] = fmaf(pv, vb[(size_t)u * HD + e0 + i], acc[i]);
        }
        const float cf = coef[tq];
        float* dst = att + (size_t)(c * CSZ + tq) * D_MODEL + h * HD + e0;
        #pragma unroll
        for (int i = 0; i < 16; ++i) dst[i] += acc[i] * cf;
    }
}

extern "C" void kernel_launch(void* const* d_in, const int* in_sizes, int n_in,
                              void* d_out, int out_size, void* d_ws, size_t ws_size,
                              hipStream_t stream)
{
    const float* x  = (const float*)d_in[0];
    const float* wq = (const float*)d_in[1];
    const float* bq = (const float*)d_in[2];
    const float* wk = (const float*)d_in[3];
    const float* bk = (const float*)d_in[4];
    const float* wv = (const float*)d_in[5];
    const float* bv = (const float*)d_in[6];
    const float* wo = (const float*)d_in[7];
    const float* bo = (const float*)d_in[8];
    float* out = (float*)d_out;

    float* ws = (float*)d_ws;
    const size_t NTD = (size_t)T_SEQ * D_MODEL;  // 1M floats
    float* qh  = ws;
    float* kh  = qh + NTD;
    float* vh  = kh + NTD;
    float* qf  = vh + NTD;
    float* kf  = qf + NTD;
    float* att = kf + NTD;
    float* Ac  = att + NTD;
    float* Sx  = Ac + NTD;
    float* bc  = Sx + NTD;                 // 8*32*64 = 16384
    float* sx  = bc + 16384;
    float* marg = sx + 16384;              // 8*2048

    dim3 b256(256);
    proj_qkv_kernel<<<dim3(32, 8, 3), b256, 0, stream>>>(x, wq, bq, wk, bk, wv, bv,
                                                         qh, kh, vh, qf, kf);
    scores_crit_kernel<<<dim3(T_SEQ, H_HEADS), b256, 0, stream>>>(qh, kh, vh, att, marg);
    chunk_sums_kernel<<<dim3(NCH, H_HEADS), b256, 0, stream>>>(kf, vh, Ac, bc);
    prefix_kernel<<<dim3(H_HEADS), b256, 0, stream>>>(Ac, bc, Sx, sx);
    lin_combine_kernel<<<dim3(NCH, H_HEADS), b256, 0, stream>>>(qf, kf, vh, Sx, sx, marg, att);
    out_proj_kernel<<<dim3(32, 8), b256, 0, stream>>>(att, wo, bo, out);
}